// Round 1
// baseline (585.066 us; speedup 1.0000x reference)
//
#include <hip/hip_runtime.h>

// Problem constants
#define B_   16
#define LD_  1024
#define LQ_  512
#define H_   1024

// Output section offsets (floats)
#define OUT0_F 0ull                  // doc_output  [B, LD, 3H] = 50331648
#define OUT1_F 50331648ull           // query_output[B, LQ, 2H] = 16777216
#define OUT2_F 67108864ull           // last        [B, 3H]     = 49152

// Workspace layout (bytes)
#define OFF_DH   0ull               // Dh  [B,LD,H] f16   33554432
#define OFF_DL   33554432ull        // Dl  (reused as DhT [B,H,LD] after scores)
#define OFF_QH   67108864ull        // Qh  [B,LQ,H] f16   16777216
#define OFF_QL   83886080ull        // Ql                 16777216
#define OFF_S    100663296ull       // S fp32 [B,LD,LQ] (reused as QoutT f16 [B,2H,LQ])
#define OFF_AD   134217728ull       // A_d f16 [B,LD,LQ]  16777216
#define OFF_AQ   150994944ull       // A_q f16 [B,LQ,LD]  16777216
#define OFF_RM   167772160ull       // rowmax [B*LD] f32
#define OFF_RI   167837696ull       // rowinv
#define OFF_CPM  167903232ull       // col partial max [B,16,LQ] f32
#define OFF_CPS  168427520ull       // col partial sum
#define OFF_CM   168951808ull       // colmax [B*LQ]
#define OFF_CI   168984576ull       // colinv
#define OFF_QLEN 169017344ull       // qlens [B] int

typedef _Float16 half8 __attribute__((ext_vector_type(8)));
typedef _Float16 half4v __attribute__((ext_vector_type(4)));
typedef float floatx4 __attribute__((ext_vector_type(4)));

// ---------------------------------------------------------------- async g->lds
__device__ __forceinline__ void gll16(const _Float16* g, _Float16* l) {
#if __has_builtin(__builtin_amdgcn_global_load_lds)
  __builtin_amdgcn_global_load_lds(
      (const __attribute__((address_space(1))) unsigned int*)(unsigned long long)g,
      (__attribute__((address_space(3))) unsigned int*)(unsigned int)(unsigned long long)l,
      16, 0, 0);
#else
  int lane = threadIdx.x & 63;
  *(half8*)(l + lane * 8) = *(const half8*)(g + lane * 8);
#endif
}

// -------------------------------------------------------- q_lens from mask buf
// query_mask is bool in the reference; storage may be u8(0/1), i32(0/1) or f32.
__global__ void k_qlens(const unsigned char* qm, int* qlens) {
  __shared__ unsigned or_hi, is_f32;
  if (threadIdx.x == 0) { or_hi = 0u; is_f32 = 0u; }
  __syncthreads();
  const unsigned* w = (const unsigned*)qm;
  unsigned lo = 0u, lf = 0u;
  for (int i = threadIdx.x; i < (B_ * LQ_) / 4; i += 256) {  // first B*LQ bytes: safe for all
    unsigned v = w[i];
    lo |= (v >> 8);
    if (v == 0x3F800000u) lf = 1u;
  }
  atomicOr(&or_hi, lo);
  atomicOr(&is_f32, lf);
  __syncthreads();
  int esize4 = (or_hi == 0u) || is_f32;  // i32/f32 -> 4B elems (zero elem == zero word)
  if (threadIdx.x < B_) {
    int b = threadIdx.x, cnt = 0;
    if (esize4) {
      const unsigned* p = (const unsigned*)qm + b * LQ_;
      for (int i = 0; i < LQ_; ++i) cnt += (p[i] == 0u);
    } else {
      const unsigned char* p = qm + b * LQ_;
      for (int i = 0; i < LQ_; ++i) cnt += (p[i] == 0);
    }
    qlens[b] = cnt;
  }
}

// ------------------------------------------------- cast/split + passthru copies
__global__ void k_cast(const float* __restrict__ Dp, const float* __restrict__ Qp,
                       _Float16* __restrict__ Dh, _Float16* __restrict__ Dl,
                       _Float16* __restrict__ Qh, _Float16* __restrict__ Ql,
                       float* __restrict__ out) {
  int t = blockIdx.x * 256 + threadIdx.x;
  const int nd4 = (B_ * LD_ * H_) / 4;
  const int nq4 = (B_ * LQ_ * H_) / 4;
  if (t < nd4) {
    float4 v = ((const float4*)Dp)[t];
    half4v hi, lo;
    hi[0] = (_Float16)v.x; lo[0] = (_Float16)(v.x - (float)hi[0]);
    hi[1] = (_Float16)v.y; lo[1] = (_Float16)(v.y - (float)hi[1]);
    hi[2] = (_Float16)v.z; lo[2] = (_Float16)(v.z - (float)hi[2]);
    hi[3] = (_Float16)v.w; lo[3] = (_Float16)(v.w - (float)hi[3]);
    ((half4v*)Dh)[t] = hi;
    ((half4v*)Dl)[t] = lo;
    int idx = t << 2, h = idx & (H_ - 1), bl = idx >> 10;
    *(float4*)(out + OUT0_F + (size_t)bl * 3072 + 2048 + h) = v;  // doc_output[:,:,2H:3H] = D
  } else if (t < nd4 + nq4) {
    int u = t - nd4;
    float4 v = ((const float4*)Qp)[u];
    half4v hi, lo;
    hi[0] = (_Float16)v.x; lo[0] = (_Float16)(v.x - (float)hi[0]);
    hi[1] = (_Float16)v.y; lo[1] = (_Float16)(v.y - (float)hi[1]);
    hi[2] = (_Float16)v.z; lo[2] = (_Float16)(v.z - (float)hi[2]);
    hi[3] = (_Float16)v.w; lo[3] = (_Float16)(v.w - (float)hi[3]);
    ((half4v*)Qh)[u] = hi;
    ((half4v*)Ql)[u] = lo;
    int idx = u << 2, h = idx & (H_ - 1), bq = idx >> 10;
    *(float4*)(out + OUT1_F + (size_t)bq * 2048 + h) = v;         // query_output[:,:,0:H] = Q
  }
}

// ------------------------------------------------ scores: S = Dh Qh^T + cross
__global__ __launch_bounds__(256) void k_gemm_scores(
    const _Float16* __restrict__ Dh, const _Float16* __restrict__ Dl,
    const _Float16* __restrict__ Qh, const _Float16* __restrict__ Ql,
    float* __restrict__ S) {
  int bid = blockIdx.x;
  int b = bid >> 5, t = bid & 31, tm = t >> 2, tn = t & 3;
  const int K = H_;
  const _Float16* Ah = Dh + (size_t)b * LD_ * H_;
  const _Float16* Al = Dl + (size_t)b * LD_ * H_;
  const _Float16* Bh = Qh + (size_t)b * LQ_ * H_;
  const _Float16* Bl = Ql + (size_t)b * LQ_ * H_;
  float* Cb = S + (size_t)b * LD_ * LQ_;

  __shared__ _Float16 sAh[128 * 32], sAl[128 * 32], sBh[128 * 32], sBl[128 * 32];
  int lane = threadIdx.x & 63, wave = threadIdx.x >> 6;
  int wm = wave >> 1, wn = wave & 1;
  int m0 = tm << 7, n0 = tn << 7;
  int srow = lane >> 2, scol = (lane & 3) << 3;

  floatx4 acc[4][4];
  floatx4 z = {0.f, 0.f, 0.f, 0.f};
#pragma unroll
  for (int i = 0; i < 4; ++i)
#pragma unroll
    for (int j = 0; j < 4; ++j) acc[i][j] = z;

  for (int k0 = 0; k0 < K; k0 += 32) {
#pragma unroll
    for (int ts = 0; ts < 2; ++ts) {
      int row = (wave << 5) + (ts << 4) + srow;
      int lo = ((wave << 5) + (ts << 4)) << 5;
      size_t ga = (size_t)(m0 + row) * K + k0 + scol;
      size_t gb = (size_t)(n0 + row) * K + k0 + scol;
      gll16(Ah + ga, sAh + lo);
      gll16(Al + ga, sAl + lo);
      gll16(Bh + gb, sBh + lo);
      gll16(Bl + gb, sBl + lo);
    }
    __syncthreads();
    int lk = (lane >> 4) << 3, lr = lane & 15;
    half8 ah[4], al4[4], bh[4], bl4[4];
#pragma unroll
    for (int i = 0; i < 4; ++i) {
      int ar = ((wm << 6) + (i << 4) + lr) << 5;
      int br = ((wn << 6) + (i << 4) + lr) << 5;
      ah[i]  = *(const half8*)(sAh + ar + lk);
      al4[i] = *(const half8*)(sAl + ar + lk);
      bh[i]  = *(const half8*)(sBh + br + lk);
      bl4[i] = *(const half8*)(sBl + br + lk);
    }
#pragma unroll
    for (int i = 0; i < 4; ++i)
#pragma unroll
      for (int j = 0; j < 4; ++j) {
        acc[i][j] = __builtin_amdgcn_mfma_f32_16x16x32_f16(ah[i],  bh[j],  acc[i][j], 0, 0, 0);
        acc[i][j] = __builtin_amdgcn_mfma_f32_16x16x32_f16(ah[i],  bl4[j], acc[i][j], 0, 0, 0);
        acc[i][j] = __builtin_amdgcn_mfma_f32_16x16x32_f16(al4[i], bh[j],  acc[i][j], 0, 0, 0);
      }
    __syncthreads();
  }
#pragma unroll
  for (int i = 0; i < 4; ++i) {
    int mb = m0 + (wm << 6) + (i << 4) + ((lane >> 4) << 2);
#pragma unroll
    for (int j = 0; j < 4; ++j) {
      int n = n0 + (wn << 6) + (j << 4) + (lane & 15);
#pragma unroll
      for (int rr = 0; rr < 4; ++rr)
        Cb[(size_t)(mb + rr) * LQ_ + n] = acc[i][j][rr];
    }
  }
}

// ---------------------------------------- softmax stats: rows full, cols partial
__global__ void k_stats(const float* __restrict__ S, const int* qlens, const int* dlens,
                        float* rowmax, float* rowinv, float* colpM, float* colpS) {
  int b = blockIdx.x >> 4, ch = blockIdx.x & 15;
  int lane = threadIdx.x & 63, wave = threadIdx.x >> 6;
  int qlen = qlens[b], dlen = dlens[b];
  const float* Sb = S + (size_t)b * LD_ * LQ_;
  float cm[8], cs[8];
#pragma unroll
  for (int j = 0; j < 8; ++j) { cm[j] = -1e30f; cs[j] = 0.f; }
  for (int ri = 0; ri < 16; ++ri) {
    int d = (ch << 6) + (wave << 4) + ri;
    const float* row = Sb + (size_t)d * LQ_;
    float v[8], rm = -1e30f;
#pragma unroll
    for (int j = 0; j < 8; ++j) {
      int q = lane + (j << 6);
      v[j] = row[q];
      if (q < qlen) rm = fmaxf(rm, v[j]);
    }
    float rs = 0.f;
#pragma unroll
    for (int j = 0; j < 8; ++j) {
      int q = lane + (j << 6);
      if (q < qlen) rs += __expf(v[j] - rm);
    }
#pragma unroll
    for (int off = 32; off > 0; off >>= 1) {
      float om = __shfl_down(rm, off);
      float os = __shfl_down(rs, off);
      float nm = fmaxf(rm, om);
      rs = rs * __expf(rm - nm) + os * __expf(om - nm);
      rm = nm;
    }
    if (lane == 0) { rowmax[b * LD_ + d] = rm; rowinv[b * LD_ + d] = 1.0f / rs; }
    if (d < dlen) {
#pragma unroll
      for (int j = 0; j < 8; ++j) {
        float x = v[j];
        float nm = fmaxf(cm[j], x);
        cs[j] = cs[j] * __expf(cm[j] - nm) + __expf(x - nm);
        cm[j] = nm;
      }
    }
  }
  __shared__ float lm[4][512], ls[4][512];
#pragma unroll
  for (int j = 0; j < 8; ++j) {
    lm[wave][lane + (j << 6)] = cm[j];
    ls[wave][lane + (j << 6)] = cs[j];
  }
  __syncthreads();
  for (int q = threadIdx.x; q < 512; q += 256) {
    float m = lm[0][q], s = ls[0][q];
#pragma unroll
    for (int w = 1; w < 4; ++w) {
      float pm = lm[w][q], ps = ls[w][q];
      float nm = fmaxf(m, pm);
      s = s * __expf(m - nm) + ps * __expf(pm - nm);
      m = nm;
    }
    colpM[((b << 4) + ch) * LQ_ + q] = m;
    colpS[((b << 4) + ch) * LQ_ + q] = s;
  }
}

__global__ void k_colmerge(const float* colpM, const float* colpS,
                           float* colmax, float* colinv) {
  int t = blockIdx.x * 256 + threadIdx.x;  // B*LQ = 8192
  int b = t >> 9, q = t & 511;
  float m = -1e30f, s = 0.f;
  for (int ch = 0; ch < 16; ++ch) {
    float pm = colpM[((b << 4) + ch) * LQ_ + q];
    float ps = colpS[((b << 4) + ch) * LQ_ + q];
    float nm = fmaxf(m, pm);
    s = s * __expf(m - nm) + ps * __expf(pm - nm);
    m = nm;
  }
  colmax[t] = m;
  colinv[t] = 1.0f / s;
}

// ----------------------------- normalize: A_d row-major, A_q via LDS transpose
__global__ void k_normalize(const float* __restrict__ S,
                            const float* rowmax, const float* rowinv,
                            const float* colmax, const float* colinv,
                            const int* qlens, const int* dlens,
                            _Float16* __restrict__ Ad, _Float16* __restrict__ Aq) {
  int blk = blockIdx.x;
  int b = blk >> 7, rest = blk & 127, dt = rest >> 3, qt = rest & 7;
  int d0 = dt << 6, q0 = qt << 6;
  int c = threadIdx.x & 63, w = threadIdx.x >> 6;
  int qlen = qlens[b], dlen = dlens[b];
  __shared__ _Float16 T[64 * 66];
  const float* Sb = S + (size_t)b * LD_ * LQ_;
  int q = q0 + c;
  float cmq = colmax[(b << 9) + q], ciq = colinv[(b << 9) + q];
  for (int i = 0; i < 16; ++i) {
    int r = (i << 2) + w, d = d0 + r;
    float s = Sb[(size_t)d * LQ_ + q];
    float ad = (q < qlen) ? __expf(s - rowmax[(b << 10) + d]) * rowinv[(b << 10) + d] : 0.f;
    Ad[(size_t)b * LD_ * LQ_ + (size_t)d * LQ_ + q] = (_Float16)ad;
    float aq = (d < dlen) ? __expf(s - cmq) * ciq : 0.f;
    T[c * 66 + r] = (_Float16)aq;
  }
  __syncthreads();
  for (int i = 0; i < 16; ++i) {
    int rq = (i << 2) + w;
    Aq[(size_t)b * LQ_ * LD_ + (size_t)(q0 + rq) * LD_ + d0 + c] = T[rq * 66 + c];
  }
}

// ------------------------------------- f16 tiled transposes: DhT and QoutT[0:H]
__global__ void k_transpose(const _Float16* __restrict__ Dh, const _Float16* __restrict__ Qh,
                            _Float16* __restrict__ DhT, _Float16* __restrict__ QT) {
  int bid = blockIdx.x;
  const _Float16* src;
  _Float16* dst;
  int ld_out, r0, c0;
  if (bid < 4096) {  // D: [LD,H] -> [H,LD], 16x16 tiles per batch
    int b = bid >> 8, t = bid & 255, tr = t >> 4, tc = t & 15;
    src = Dh + (size_t)b * LD_ * H_;
    dst = DhT + (size_t)b * H_ * LD_;
    ld_out = LD_; r0 = tr << 6; c0 = tc << 6;
  } else {           // Q: [LQ,H] -> QT[0:H], 8x16 tiles per batch
    int t2 = bid - 4096;
    int b = t2 >> 7, t = t2 & 127, tr = t >> 4, tc = t & 15;
    src = Qh + (size_t)b * LQ_ * H_;
    dst = QT + (size_t)b * 2 * H_ * LQ_;
    ld_out = LQ_; r0 = tr << 6; c0 = tc << 6;
  }
  int c = threadIdx.x & 63, w = threadIdx.x >> 6;
  __shared__ _Float16 T[64 * 66];
  for (int i = 0; i < 16; ++i) {
    int r = (i << 2) + w;
    T[c * 66 + r] = src[(size_t)(r0 + r) * H_ + c0 + c];
  }
  __syncthreads();
  for (int i = 0; i < 16; ++i) {
    int r = (i << 2) + w;
    dst[(size_t)(c0 + r) * ld_out + r0 + c] = T[r * 66 + c];
  }
}

// --------------------- C_q^T = DhT(A) x Aq(B): writes query_output + QoutT[H:2H]
__global__ __launch_bounds__(256) void k_gemm_cq(const _Float16* __restrict__ DhT,
                                                 const _Float16* __restrict__ Aq,
                                                 _Float16* __restrict__ QT,
                                                 float* __restrict__ out) {
  int bid = blockIdx.x;
  int b = bid >> 5, t = bid & 31, tm = t >> 2, tn = t & 3;
  const int K = LD_;
  const _Float16* A = DhT + (size_t)b * H_ * LD_;
  const _Float16* Bm = Aq + (size_t)b * LQ_ * LD_;
  __shared__ _Float16 sA[128 * 32], sB[128 * 32];
  int lane = threadIdx.x & 63, wave = threadIdx.x >> 6;
  int wm = wave >> 1, wn = wave & 1;
  int m0 = tm << 7, n0 = tn << 7;
  int srow = lane >> 2, scol = (lane & 3) << 3;

  floatx4 acc[4][4];
  floatx4 z = {0.f, 0.f, 0.f, 0.f};
#pragma unroll
  for (int i = 0; i < 4; ++i)
#pragma unroll
    for (int j = 0; j < 4; ++j) acc[i][j] = z;

  for (int k0 = 0; k0 < K; k0 += 32) {
#pragma unroll
    for (int ts = 0; ts < 2; ++ts) {
      int row = (wave << 5) + (ts << 4) + srow;
      int lo = ((wave << 5) + (ts << 4)) << 5;
      gll16(A + (size_t)(m0 + row) * K + k0 + scol, sA + lo);
      gll16(Bm + (size_t)(n0 + row) * K + k0 + scol, sB + lo);
    }
    __syncthreads();
    int lk = (lane >> 4) << 3, lr = lane & 15;
    half8 af[4], bf[4];
#pragma unroll
    for (int i = 0; i < 4; ++i) {
      af[i] = *(const half8*)(sA + (((wm << 6) + (i << 4) + lr) << 5) + lk);
      bf[i] = *(const half8*)(sB + (((wn << 6) + (i << 4) + lr) << 5) + lk);
    }
#pragma unroll
    for (int i = 0; i < 4; ++i)
#pragma unroll
      for (int j = 0; j < 4; ++j)
        acc[i][j] = __builtin_amdgcn_mfma_f32_16x16x32_f16(af[i], bf[j], acc[i][j], 0, 0, 0);
    __syncthreads();
  }
  float* qoutb = out + OUT1_F + (size_t)b * LQ_ * 2048;
  _Float16* qtb = QT + (size_t)b * 2048 * LQ_;
#pragma unroll
  for (int i = 0; i < 4; ++i) {
    int m = m0 + (wm << 6) + (i << 4) + ((lane >> 4) << 2);  // h index (4-aligned)
#pragma unroll
    for (int j = 0; j < 4; ++j) {
      int n = n0 + (wn << 6) + (j << 4) + (lane & 15);       // q index
      float4 v;
      v.x = acc[i][j][0]; v.y = acc[i][j][1]; v.z = acc[i][j][2]; v.w = acc[i][j][3];
      *(float4*)(qoutb + (size_t)n * 2048 + 1024 + m) = v;   // query_output[:,q,H+h]
#pragma unroll
      for (int rr = 0; rr < 4; ++rr)
        qtb[(size_t)(1024 + m + rr) * LQ_ + n] = (_Float16)acc[i][j][rr];
    }
  }
}

// ---------------------------- C_D = Ad(A) x QoutT(B): doc_output[:, :, 0:2H]
__global__ __launch_bounds__(256) void k_gemm_cd(const _Float16* __restrict__ Ad,
                                                 const _Float16* __restrict__ QT,
                                                 float* __restrict__ out) {
  int bid = blockIdx.x;
  int b = bid >> 7, t = bid & 127, tm = t >> 4, tn = t & 15;
  const int K = LQ_;
  const _Float16* A = Ad + (size_t)b * LD_ * LQ_;
  const _Float16* Bm = QT + (size_t)b * 2048 * LQ_;
  __shared__ _Float16 sA[128 * 32], sB[128 * 32];
  int lane = threadIdx.x & 63, wave = threadIdx.x >> 6;
  int wm = wave >> 1, wn = wave & 1;
  int m0 = tm << 7, n0 = tn << 7;
  int srow = lane >> 2, scol = (lane & 3) << 3;

  floatx4 acc[4][4];
  floatx4 z = {0.f, 0.f, 0.f, 0.f};
#pragma unroll
  for (int i = 0; i < 4; ++i)
#pragma unroll
    for (int j = 0; j < 4; ++j) acc[i][j] = z;

  for (int k0 = 0; k0 < K; k0 += 32) {
#pragma unroll
    for (int ts = 0; ts < 2; ++ts) {
      int row = (wave << 5) + (ts << 4) + srow;
      int lo = ((wave << 5) + (ts << 4)) << 5;
      gll16(A + (size_t)(m0 + row) * K + k0 + scol, sA + lo);
      gll16(Bm + (size_t)(n0 + row) * K + k0 + scol, sB + lo);
    }
    __syncthreads();
    int lk = (lane >> 4) << 3, lr = lane & 15;
    half8 af[4], bf[4];
#pragma unroll
    for (int i = 0; i < 4; ++i) {
      af[i] = *(const half8*)(sA + (((wm << 6) + (i << 4) + lr) << 5) + lk);
      bf[i] = *(const half8*)(sB + (((wn << 6) + (i << 4) + lr) << 5) + lk);
    }
#pragma unroll
    for (int i = 0; i < 4; ++i)
#pragma unroll
      for (int j = 0; j < 4; ++j)
        acc[i][j] = __builtin_amdgcn_mfma_f32_16x16x32_f16(af[i], bf[j], acc[i][j], 0, 0, 0);
    __syncthreads();
  }
  float* db = out + OUT0_F + (size_t)b * LD_ * 3072;
#pragma unroll
  for (int i = 0; i < 4; ++i) {
    int mb = m0 + (wm << 6) + (i << 4) + ((lane >> 4) << 2);
#pragma unroll
    for (int j = 0; j < 4; ++j) {
      int n = n0 + (wn << 6) + (j << 4) + (lane & 15);
#pragma unroll
      for (int rr = 0; rr < 4; ++rr)
        db[(size_t)(mb + rr) * 3072 + n] = acc[i][j][rr];
    }
  }
}

// --------------------------------------------------------------- last gather
__global__ void k_last(const int* dlens, float* __restrict__ out) {
  int t = blockIdx.x * 256 + threadIdx.x;  // B*3H = 49152
  int b = t / 3072, i = t % 3072;
  out[OUT2_F + t] = out[OUT0_F + (size_t)b * LD_ * 3072 + (size_t)(dlens[b] - 1) * 3072 + i];
}

// ------------------------------------------------------------------- launcher
extern "C" void kernel_launch(void* const* d_in, const int* in_sizes, int n_in,
                              void* d_out, int out_size, void* d_ws, size_t ws_size,
                              hipStream_t stream) {
  const float* Dp = (const float*)d_in[0];
  const float* Qp = (const float*)d_in[1];
  const unsigned char* qmask = (const unsigned char*)d_in[3];
  const int* dlens = (const int*)d_in[4];
  float* out = (float*)d_out;
  char* ws = (char*)d_ws;

  _Float16* Dh  = (_Float16*)(ws + OFF_DH);
  _Float16* Dl  = (_Float16*)(ws + OFF_DL);
  _Float16* Qh  = (_Float16*)(ws + OFF_QH);
  _Float16* Ql  = (_Float16*)(ws + OFF_QL);
  float*    S   = (float*)(ws + OFF_S);
  _Float16* Ad  = (_Float16*)(ws + OFF_AD);
  _Float16* Aq  = (_Float16*)(ws + OFF_AQ);
  float*    rm  = (float*)(ws + OFF_RM);
  float*    ri  = (float*)(ws + OFF_RI);
  float*    cpm = (float*)(ws + OFF_CPM);
  float*    cps = (float*)(ws + OFF_CPS);
  float*    cm  = (float*)(ws + OFF_CM);
  float*    ci  = (float*)(ws + OFF_CI);
  int*      ql  = (int*)(ws + OFF_QLEN);
  _Float16* DhT = (_Float16*)(ws + OFF_DL);  // aliases Dl (dead after scores)
  _Float16* QT  = (_Float16*)(ws + OFF_S);   // aliases S  (dead after normalize)

  k_qlens<<<1, 256, 0, stream>>>(qmask, ql);
  k_cast<<<24576, 256, 0, stream>>>(Dp, Qp, Dh, Dl, Qh, Ql, out);
  k_gemm_scores<<<512, 256, 0, stream>>>(Dh, Dl, Qh, Ql, S);
  k_stats<<<256, 256, 0, stream>>>(S, ql, dlens, rm, ri, cpm, cps);
  k_colmerge<<<32, 256, 0, stream>>>(cpm, cps, cm, ci);
  k_normalize<<<2048, 256, 0, stream>>>(S, rm, ri, cm, ci, ql, dlens, Ad, Aq);
  k_transpose<<<6144, 256, 0, stream>>>(Dh, Qh, DhT, QT);
  k_gemm_cq<<<512, 256, 0, stream>>>(DhT, Aq, QT, out);
  k_gemm_cd<<<2048, 256, 0, stream>>>(Ad, QT, out);
  k_last<<<192, 256, 0, stream>>>(dlens, out);
}

// Round 2
// 584.627 us; speedup vs baseline: 1.0008x; 1.0008x over previous
//
#include <hip/hip_runtime.h>

#define B_   16
#define LD_  1024
#define LQ_  512
#define H_   1024

// Output section offsets (floats)
#define OUT0_F 0ull                  // doc_output  [B, LD, 3H]
#define OUT1_F 50331648ull           // query_output[B, LQ, 2H]
#define OUT2_F 67108864ull           // last        [B, 3H]

// Workspace layout (bytes) — ws is ~1 GiB, no aliasing needed
#define OFF_DH   0ull               // Dh  [B,LD,H] f16  32MB
#define OFF_DL   33554432ull        // Dl  32MB
#define OFF_QH   67108864ull        // Qh  16MB
#define OFF_QL   83886080ull        // Ql  16MB
#define OFF_S    100663296ull       // S fp32 [B,LD,LQ] 32MB
#define OFF_AD   134217728ull       // A_d f16 [B,LD,LQ] 16MB
#define OFF_AQ   150994944ull       // A_q f16 [B,LQ,LD] 16MB
#define OFF_DHT  167772160ull       // DhT [B,H,LD] f16 32MB
#define OFF_QT   201326592ull       // QoutT [B,2H,LQ] f16 32MB
#define OFF_RM   234881024ull       // rowmax [B*LD] f32
#define OFF_RI   234946560ull
#define OFF_CM   235012096ull       // colmax [B*LQ]
#define OFF_CI   235044864ull
#define OFF_QLEN 235077632ull
#define OFF_RPM  235077888ull       // row partial max [4][B*LD]
#define OFF_RPS  235340032ull
#define OFF_CPM  235602176ull       // col partial max [8][B*LQ]
#define OFF_CPS  235864320ull

typedef _Float16 half8 __attribute__((ext_vector_type(8)));
typedef _Float16 half4v __attribute__((ext_vector_type(4)));
typedef float floatx4 __attribute__((ext_vector_type(4)));

// ---------------------------------------------------------------- async g->lds
__device__ __forceinline__ void gll16(const _Float16* g, _Float16* l) {
#if __has_builtin(__builtin_amdgcn_global_load_lds)
  __builtin_amdgcn_global_load_lds(
      (const __attribute__((address_space(1))) unsigned int*)(unsigned long long)g,
      (__attribute__((address_space(3))) unsigned int*)(unsigned int)(unsigned long long)l,
      16, 0, 0);
#else
  int lane = threadIdx.x & 63;
  *(half8*)(l + lane * 8) = *(const half8*)(g + lane * 8);
#endif
}

__device__ __forceinline__ void omerge(float& m, float& s, float pm, float ps) {
  float nm = fmaxf(m, pm);
  s = s * __expf(m - nm) + ps * __expf(pm - nm);
  m = nm;
}

// -------------------------------------------------------- q_lens from mask buf
__global__ void k_qlens(const unsigned char* qm, int* qlens) {
  __shared__ unsigned or_hi, is_f32;
  __shared__ int scnt[B_];
  if (threadIdx.x == 0) { or_hi = 0u; is_f32 = 0u; }
  if (threadIdx.x < B_) scnt[threadIdx.x] = 0;
  __syncthreads();
  const unsigned* w = (const unsigned*)qm;
  unsigned lo = 0u, lf = 0u;
  for (int i = threadIdx.x; i < (B_ * LQ_) / 4; i += 256) {
    unsigned v = w[i];
    lo |= (v >> 8);
    if (v == 0x3F800000u) lf = 1u;
  }
  if (lo) atomicOr(&or_hi, 1u);
  if (lf) atomicOr(&is_f32, 1u);
  __syncthreads();
  int esize4 = (or_hi == 0u) || is_f32;  // i32/f32 storage
  for (int idx = threadIdx.x; idx < B_ * LQ_; idx += 256) {
    int b = idx >> 9;
    int z;
    if (esize4) z = (((const unsigned*)qm)[idx] == 0u);
    else        z = (qm[idx] == 0);
    if (z) atomicAdd(&scnt[b], 1);
  }
  __syncthreads();
  if (threadIdx.x < B_) qlens[threadIdx.x] = scnt[threadIdx.x];
}

// -------------------- cast/split + fp32 passthru copies + fused f16 transposes
__global__ __launch_bounds__(256) void k_cast(
    const float* __restrict__ Dp, const float* __restrict__ Qp,
    const int* __restrict__ dlens,
    _Float16* __restrict__ Dh, _Float16* __restrict__ Dl,
    _Float16* __restrict__ Qh, _Float16* __restrict__ Ql,
    _Float16* __restrict__ DhT, _Float16* __restrict__ QT,
    float* __restrict__ out) {
  __shared__ _Float16 T[64 * 66];
  int bid = blockIdx.x;
  int t = threadIdx.x;
  int r = t >> 2, cb = (t & 3) << 4;
  bool isD = bid < 4096;
  int b, r0, c0;
  const float* src;
  if (isD) {   // D: [LD,H] 16x16 tiles of 64x64 per batch
    b = bid >> 8; int rest = bid & 255; r0 = (rest >> 4) << 6; c0 = (rest & 15) << 6;
    src = Dp + (size_t)b * LD_ * H_;
  } else {     // Q: [LQ,H] 8x16 tiles per batch
    int t2 = bid - 4096;
    b = t2 >> 7; int rest = t2 & 127; r0 = (rest >> 4) << 6; c0 = (rest & 15) << 6;
    src = Qp + (size_t)b * LQ_ * H_;
  }
  size_t eoff = (size_t)(r0 + r) * H_ + c0 + cb;
  float4 v[4];
#pragma unroll
  for (int k = 0; k < 4; ++k) v[k] = *(const float4*)(src + eoff + (k << 2));
  half4v hi4[4], lo4[4];
#pragma unroll
  for (int k = 0; k < 4; ++k) {
    const float* f = (const float*)&v[k];
#pragma unroll
    for (int e = 0; e < 4; ++e) {
      _Float16 h = (_Float16)f[e];
      hi4[k][e] = h;
      lo4[k][e] = (_Float16)(f[e] - (float)h);
    }
  }
  if (isD) {
    _Float16* dh = Dh + (size_t)b * LD_ * H_ + eoff;
    _Float16* dl = Dl + (size_t)b * LD_ * H_ + eoff;
    float* dob = out + OUT0_F + (size_t)b * LD_ * 3072 + (size_t)(r0 + r) * 3072 + 2048 + c0 + cb;
#pragma unroll
    for (int k = 0; k < 4; ++k) {
      *(half4v*)(dh + (k << 2)) = hi4[k];
      *(half4v*)(dl + (k << 2)) = lo4[k];
      *(float4*)(dob + (k << 2)) = v[k];
    }
    if (r0 + r == dlens[b] - 1) {
      float* o2 = out + OUT2_F + (size_t)b * 3072 + 2048 + c0 + cb;
#pragma unroll
      for (int k = 0; k < 4; ++k) *(float4*)(o2 + (k << 2)) = v[k];
    }
  } else {
    _Float16* qh = Qh + (size_t)b * LQ_ * H_ + eoff;
    _Float16* ql = Ql + (size_t)b * LQ_ * H_ + eoff;
    float* qob = out + OUT1_F + (size_t)b * LQ_ * 2048 + (size_t)(r0 + r) * 2048 + c0 + cb;
#pragma unroll
    for (int k = 0; k < 4; ++k) {
      *(half4v*)(qh + (k << 2)) = hi4[k];
      *(half4v*)(ql + (k << 2)) = lo4[k];
      *(float4*)(qob + (k << 2)) = v[k];
    }
  }
  // LDS transpose of hi
#pragma unroll
  for (int k = 0; k < 4; ++k)
#pragma unroll
    for (int e = 0; e < 4; ++e)
      T[r * 66 + cb + (k << 2) + e] = hi4[k][e];
  __syncthreads();
  int ho = t >> 2, wb = (t & 3) << 4;
  half4v o[4];
#pragma unroll
  for (int k = 0; k < 4; ++k)
#pragma unroll
    for (int e = 0; e < 4; ++e)
      o[k][e] = T[(wb + (k << 2) + e) * 66 + ho];
  if (isD) {
    _Float16* dt = DhT + (size_t)b * H_ * LD_ + (size_t)(c0 + ho) * LD_ + r0 + wb;
#pragma unroll
    for (int k = 0; k < 4; ++k) *(half4v*)(dt + (k << 2)) = o[k];
  } else {
    _Float16* qt = QT + (size_t)b * 2048 * LQ_ + (size_t)(c0 + ho) * LQ_ + r0 + wb;
#pragma unroll
    for (int k = 0; k < 4; ++k) *(half4v*)(qt + (k << 2)) = o[k];
  }
}

// ---------------- scores: S = Dh Qh^T + cross terms, fused partial softmax stats
__global__ __launch_bounds__(256) void k_gemm_scores(
    const _Float16* __restrict__ Dh, const _Float16* __restrict__ Dl,
    const _Float16* __restrict__ Qh, const _Float16* __restrict__ Ql,
    float* __restrict__ S, const int* __restrict__ qlens, const int* __restrict__ dlens,
    float* __restrict__ rowPM, float* __restrict__ rowPS,
    float* __restrict__ colPM, float* __restrict__ colPS) {
  int raw = blockIdx.x;                       // 512 blocks; XCD-swizzle: batch per XCD
  int xcd = raw & 7, idx = raw >> 3;          // idx 0..63
  int b = xcd + ((idx >> 5) << 3);            // 2 batches per XCD
  int t = idx & 31, tm = t >> 2, tn = t & 3;  // 8 m-tiles, 4 n-tiles
  const int K = H_;
  const _Float16* Ah = Dh + (size_t)b * LD_ * H_;
  const _Float16* Al = Dl + (size_t)b * LD_ * H_;
  const _Float16* Bh = Qh + (size_t)b * LQ_ * H_;
  const _Float16* Bl = Ql + (size_t)b * LQ_ * H_;
  float* Cb = S + (size_t)b * LD_ * LQ_;

  __shared__ _Float16 sAh[128 * 32], sAl[128 * 32], sBh[128 * 32], sBl[128 * 32];
  int lane = threadIdx.x & 63, wave = threadIdx.x >> 6;
  int wm = wave >> 1, wn = wave & 1;
  int m0 = tm << 7, n0 = tn << 7;
  int srow = lane >> 2, scol = (lane & 3) << 3;

  floatx4 acc[4][4];
  floatx4 z = {0.f, 0.f, 0.f, 0.f};
#pragma unroll
  for (int i = 0; i < 4; ++i)
#pragma unroll
    for (int j = 0; j < 4; ++j) acc[i][j] = z;

  for (int k0 = 0; k0 < K; k0 += 32) {
#pragma unroll
    for (int ts = 0; ts < 2; ++ts) {
      int row = (wave << 5) + (ts << 4) + srow;
      int lo = ((wave << 5) + (ts << 4)) << 5;
      size_t ga = (size_t)(m0 + row) * K + k0 + scol;
      size_t gb = (size_t)(n0 + row) * K + k0 + scol;
      gll16(Ah + ga, sAh + lo);
      gll16(Al + ga, sAl + lo);
      gll16(Bh + gb, sBh + lo);
      gll16(Bl + gb, sBl + lo);
    }
    __syncthreads();
    int lk = (lane >> 4) << 3, lr = lane & 15;
    half8 ah[4], al4[4], bh[4], bl4[4];
#pragma unroll
    for (int i = 0; i < 4; ++i) {
      int ar = ((wm << 6) + (i << 4) + lr) << 5;
      int br = ((wn << 6) + (i << 4) + lr) << 5;
      ah[i]  = *(const half8*)(sAh + ar + lk);
      al4[i] = *(const half8*)(sAl + ar + lk);
      bh[i]  = *(const half8*)(sBh + br + lk);
      bl4[i] = *(const half8*)(sBl + br + lk);
    }
#pragma unroll
    for (int i = 0; i < 4; ++i)
#pragma unroll
      for (int j = 0; j < 4; ++j) {
        acc[i][j] = __builtin_amdgcn_mfma_f32_16x16x32_f16(ah[i],  bh[j],  acc[i][j], 0, 0, 0);
        acc[i][j] = __builtin_amdgcn_mfma_f32_16x16x32_f16(ah[i],  bl4[j], acc[i][j], 0, 0, 0);
        acc[i][j] = __builtin_amdgcn_mfma_f32_16x16x32_f16(al4[i], bh[j],  acc[i][j], 0, 0, 0);
      }
    __syncthreads();
  }
  int quad = lane >> 4, l15 = lane & 15;
  // store S
#pragma unroll
  for (int i = 0; i < 4; ++i) {
    int mb = m0 + (wm << 6) + (i << 4) + (quad << 2);
#pragma unroll
    for (int j = 0; j < 4; ++j) {
      int n = n0 + (wn << 6) + (j << 4) + l15;
#pragma unroll
      for (int rr = 0; rr < 4; ++rr)
        Cb[(size_t)(mb + rr) * LQ_ + n] = acc[i][j][rr];
    }
  }
  // ---- fused partial softmax stats (reuse LDS) ----
  int qlen = qlens[b], dlen = dlens[b];
  float* redM = (float*)sAh;  // [128][2]
  float* redS = (float*)sAl;
  float* cdM  = (float*)sBh;  // [128][2]
  float* cdS  = (float*)sBl;
  // row partials: per row, over this block's 128 cols (q < qlen mask)
#pragma unroll
  for (int i = 0; i < 4; ++i) {
#pragma unroll
    for (int rr = 0; rr < 4; ++rr) {
      float mx = -1e30f;
#pragma unroll
      for (int j = 0; j < 4; ++j) {
        int q = n0 + (wn << 6) + (j << 4) + l15;
        if (q < qlen) mx = fmaxf(mx, acc[i][j][rr]);
      }
      float s = 0.f;
#pragma unroll
      for (int j = 0; j < 4; ++j) {
        int q = n0 + (wn << 6) + (j << 4) + l15;
        if (q < qlen) s += __expf(acc[i][j][rr] - mx);
      }
#pragma unroll
      for (int off = 1; off < 16; off <<= 1) {
        float om = __shfl_xor(mx, off);
        float os = __shfl_xor(s, off);
        omerge(mx, s, om, os);
      }
      if (l15 == 0) {
        int rl = (wm << 6) + (i << 4) + (quad << 2) + rr;
        redM[(rl << 1) + wn] = mx;
        redS[(rl << 1) + wn] = s;
      }
    }
  }
  // col partials: per col, over this block's 128 rows (d < dlen mask)
#pragma unroll
  for (int j = 0; j < 4; ++j) {
    float mx = -1e30f;
#pragma unroll
    for (int i = 0; i < 4; ++i)
#pragma unroll
      for (int rr = 0; rr < 4; ++rr) {
        int d = m0 + (wm << 6) + (i << 4) + (quad << 2) + rr;
        if (d < dlen) mx = fmaxf(mx, acc[i][j][rr]);
      }
    float s = 0.f;
#pragma unroll
    for (int i = 0; i < 4; ++i)
#pragma unroll
      for (int rr = 0; rr < 4; ++rr) {
        int d = m0 + (wm << 6) + (i << 4) + (quad << 2) + rr;
        if (d < dlen) s += __expf(acc[i][j][rr] - mx);
      }
#pragma unroll
    for (int off = 16; off < 64; off <<= 1) {
      float om = __shfl_xor(mx, off);
      float os = __shfl_xor(s, off);
      omerge(mx, s, om, os);
    }
    if (quad == 0) {
      int cl = (wn << 6) + (j << 4) + l15;
      cdM[(cl << 1) + wm] = mx;
      cdS[(cl << 1) + wm] = s;
    }
  }
  __syncthreads();
  if (threadIdx.x < 128) {
    int rl = threadIdx.x;
    float m1 = redM[rl << 1], s1 = redS[rl << 1];
    omerge(m1, s1, redM[(rl << 1) + 1], redS[(rl << 1) + 1]);
    int gr = b * LD_ + m0 + rl;
    rowPM[tn * (B_ * LD_) + gr] = m1;
    rowPS[tn * (B_ * LD_) + gr] = s1;
  } else {
    int cl = threadIdx.x - 128;
    float m1 = cdM[cl << 1], s1 = cdS[cl << 1];
    omerge(m1, s1, cdM[(cl << 1) + 1], cdS[(cl << 1) + 1]);
    int gc = b * LQ_ + n0 + cl;
    colPM[tm * (B_ * LQ_) + gc] = m1;
    colPS[tm * (B_ * LQ_) + gc] = s1;
  }
}

// ------------------------------------------------- merge partial softmax stats
__global__ void k_merge(const float* __restrict__ rowPM, const float* __restrict__ rowPS,
                        const float* __restrict__ colPM, const float* __restrict__ colPS,
                        float* rm, float* ri, float* cm2, float* ci) {
  int t = blockIdx.x * 256 + threadIdx.x;
  if (t < B_ * LD_) {
    float m = -1e30f, s = 0.f;
#pragma unroll
    for (int c = 0; c < 4; ++c) omerge(m, s, rowPM[c * (B_ * LD_) + t], rowPS[c * (B_ * LD_) + t]);
    rm[t] = m; ri[t] = 1.0f / s;
  } else if (t < B_ * LD_ + B_ * LQ_) {
    int u = t - B_ * LD_;
    float m = -1e30f, s = 0.f;
#pragma unroll
    for (int c = 0; c < 8; ++c) omerge(m, s, colPM[c * (B_ * LQ_) + u], colPS[c * (B_ * LQ_) + u]);
    cm2[u] = m; ci[u] = 1.0f / s;
  }
}

// ----------------------------- normalize: A_d row-major, A_q via LDS transpose
__global__ void k_normalize(const float* __restrict__ S,
                            const float* rowmax, const float* rowinv,
                            const float* colmax, const float* colinv,
                            const int* qlens, const int* dlens,
                            _Float16* __restrict__ Ad, _Float16* __restrict__ Aq) {
  int blk = blockIdx.x;
  int b = blk >> 7, rest = blk & 127, dt = rest >> 3, qt = rest & 7;
  int d0 = dt << 6, q0 = qt << 6;
  int c = threadIdx.x & 63, w = threadIdx.x >> 6;
  int qlen = qlens[b], dlen = dlens[b];
  __shared__ _Float16 T[64 * 66];
  const float* Sb = S + (size_t)b * LD_ * LQ_;
  int q = q0 + c;
  float cmq = colmax[(b << 9) + q], ciq = colinv[(b << 9) + q];
  for (int i = 0; i < 16; ++i) {
    int r = (i << 2) + w, d = d0 + r;
    float s = Sb[(size_t)d * LQ_ + q];
    float ad = (q < qlen) ? __expf(s - rowmax[(b << 10) + d]) * rowinv[(b << 10) + d] : 0.f;
    Ad[(size_t)b * LD_ * LQ_ + (size_t)d * LQ_ + q] = (_Float16)ad;
    float aq = (d < dlen) ? __expf(s - cmq) * ciq : 0.f;
    T[c * 66 + r] = (_Float16)aq;
  }
  __syncthreads();
  for (int i = 0; i < 16; ++i) {
    int rq = (i << 2) + w;
    Aq[(size_t)b * LQ_ * LD_ + (size_t)(q0 + rq) * LD_ + d0 + c] = T[rq * 66 + c];
  }
}

// -------- C_q: m=q, n=h, k=d. A=Aq[LQ,LD], B=DhT[H,LD]. Writes qout fp32 + QT f16
__global__ __launch_bounds__(256) void k_gemm_cq(const _Float16* __restrict__ Aq,
                                                 const _Float16* __restrict__ DhT,
                                                 _Float16* __restrict__ QT,
                                                 float* __restrict__ out) {
  int raw = blockIdx.x;                       // 512
  int xcd = raw & 7, idx = raw >> 3;
  int b = xcd + ((idx >> 5) << 3);
  int t = idx & 31, tm = t >> 3, tn = t & 7;  // 4 m-tiles (q), 8 n-tiles (h)
  const int K = LD_;
  const _Float16* A = Aq + (size_t)b * LQ_ * LD_;
  const _Float16* Bm = DhT + (size_t)b * H_ * LD_;
  __shared__ _Float16 sA[128 * 32], sB[128 * 32];
  int lane = threadIdx.x & 63, wave = threadIdx.x >> 6;
  int wm = wave >> 1, wn = wave & 1;
  int m0 = tm << 7, n0 = tn << 7;
  int srow = lane >> 2, scol = (lane & 3) << 3;

  floatx4 acc[4][4];
  floatx4 z = {0.f, 0.f, 0.f, 0.f};
#pragma unroll
  for (int i = 0; i < 4; ++i)
#pragma unroll
    for (int j = 0; j < 4; ++j) acc[i][j] = z;

  for (int k0 = 0; k0 < K; k0 += 32) {
#pragma unroll
    for (int ts = 0; ts < 2; ++ts) {
      int row = (wave << 5) + (ts << 4) + srow;
      int lo = ((wave << 5) + (ts << 4)) << 5;
      gll16(A + (size_t)(m0 + row) * K + k0 + scol, sA + lo);
      gll16(Bm + (size_t)(n0 + row) * K + k0 + scol, sB + lo);
    }
    __syncthreads();
    int lk = (lane >> 4) << 3, lr = lane & 15;
    half8 af[4], bf[4];
#pragma unroll
    for (int i = 0; i < 4; ++i) {
      af[i] = *(const half8*)(sA + (((wm << 6) + (i << 4) + lr) << 5) + lk);
      bf[i] = *(const half8*)(sB + (((wn << 6) + (i << 4) + lr) << 5) + lk);
    }
#pragma unroll
    for (int i = 0; i < 4; ++i)
#pragma unroll
      for (int j = 0; j < 4; ++j)
        acc[i][j] = __builtin_amdgcn_mfma_f32_16x16x32_f16(af[i], bf[j], acc[i][j], 0, 0, 0);
    __syncthreads();
  }
  float* qoutb = out + OUT1_F + (size_t)b * LQ_ * 2048;
  _Float16* qtb = QT + (size_t)b * 2048 * LQ_;
  int quad = lane >> 4, l15 = lane & 15;
#pragma unroll
  for (int i = 0; i < 4; ++i) {
    int q = m0 + (wm << 6) + (i << 4) + (quad << 2);
#pragma unroll
    for (int j = 0; j < 4; ++j) {
      int h = n0 + (wn << 6) + (j << 4) + l15;
#pragma unroll
      for (int rr = 0; rr < 4; ++rr)
        qoutb[(size_t)(q + rr) * 2048 + 1024 + h] = acc[i][j][rr];  // coalesced over h
      half4v hv;
#pragma unroll
      for (int rr = 0; rr < 4; ++rr) hv[rr] = (_Float16)acc[i][j][rr];
      *(half4v*)(qtb + (size_t)(1024 + h) * LQ_ + q) = hv;          // 8B granule
    }
  }
}

// ---------------- C_D = Ad x QoutT: doc_output[:, :, 0:2H] + fused last gather
__global__ __launch_bounds__(256) void k_gemm_cd(const _Float16* __restrict__ Ad,
                                                 const _Float16* __restrict__ QT,
                                                 const int* __restrict__ dlens,
                                                 float* __restrict__ out) {
  int raw = blockIdx.x;                       // 2048
  int xcd = raw & 7, idx = raw >> 3;          // idx 0..255
  int b = xcd + ((idx >> 7) << 3);
  int tile = idx & 127, tm = tile >> 4, tn = tile & 15;
  const int K = LQ_;
  const _Float16* A = Ad + (size_t)b * LD_ * LQ_;
  const _Float16* Bm = QT + (size_t)b * 2048 * LQ_;
  __shared__ _Float16 sA[128 * 32], sB[128 * 32];
  int lane = threadIdx.x & 63, wave = threadIdx.x >> 6;
  int wm = wave >> 1, wn = wave & 1;
  int m0 = tm << 7, n0 = tn << 7;
  int srow = lane >> 2, scol = (lane & 3) << 3;

  floatx4 acc[4][4];
  floatx4 z = {0.f, 0.f, 0.f, 0.f};
#pragma unroll
  for (int i = 0; i < 4; ++i)
#pragma unroll
    for (int j = 0; j < 4; ++j) acc[i][j] = z;

  for (int k0 = 0; k0 < K; k0 += 32) {
#pragma unroll
    for (int ts = 0; ts < 2; ++ts) {
      int row = (wave << 5) + (ts << 4) + srow;
      int lo = ((wave << 5) + (ts << 4)) << 5;
      gll16(A + (size_t)(m0 + row) * K + k0 + scol, sA + lo);
      gll16(Bm + (size_t)(n0 + row) * K + k0 + scol, sB + lo);
    }
    __syncthreads();
    int lk = (lane >> 4) << 3, lr = lane & 15;
    half8 af[4], bf[4];
#pragma unroll
    for (int i = 0; i < 4; ++i) {
      af[i] = *(const half8*)(sA + (((wm << 6) + (i << 4) + lr) << 5) + lk);
      bf[i] = *(const half8*)(sB + (((wn << 6) + (i << 4) + lr) << 5) + lk);
    }
#pragma unroll
    for (int i = 0; i < 4; ++i)
#pragma unroll
      for (int j = 0; j < 4; ++j)
        acc[i][j] = __builtin_amdgcn_mfma_f32_16x16x32_f16(af[i], bf[j], acc[i][j], 0, 0, 0);
    __syncthreads();
  }
  float* db = out + OUT0_F + (size_t)b * LD_ * 3072;
  int dlast = dlens[b] - 1;
  int quad = lane >> 4, l15 = lane & 15;
#pragma unroll
  for (int i = 0; i < 4; ++i) {
    int mb = m0 + (wm << 6) + (i << 4) + (quad << 2);
#pragma unroll
    for (int j = 0; j < 4; ++j) {
      int n = n0 + (wn << 6) + (j << 4) + l15;
#pragma unroll
      for (int rr = 0; rr < 4; ++rr) {
        db[(size_t)(mb + rr) * 3072 + n] = acc[i][j][rr];
        if (mb + rr == dlast) out[OUT2_F + (size_t)b * 3072 + n] = acc[i][j][rr];
      }
    }
  }
}

// ------------------------------------------------------------------- launcher
extern "C" void kernel_launch(void* const* d_in, const int* in_sizes, int n_in,
                              void* d_out, int out_size, void* d_ws, size_t ws_size,
                              hipStream_t stream) {
  const float* Dp = (const float*)d_in[0];
  const float* Qp = (const float*)d_in[1];
  const unsigned char* qmask = (const unsigned char*)d_in[3];
  const int* dlens = (const int*)d_in[4];
  float* out = (float*)d_out;
  char* ws = (char*)d_ws;

  _Float16* Dh  = (_Float16*)(ws + OFF_DH);
  _Float16* Dl  = (_Float16*)(ws + OFF_DL);
  _Float16* Qh  = (_Float16*)(ws + OFF_QH);
  _Float16* Ql  = (_Float16*)(ws + OFF_QL);
  float*    S   = (float*)(ws + OFF_S);
  _Float16* Ad  = (_Float16*)(ws + OFF_AD);
  _Float16* Aq  = (_Float16*)(ws + OFF_AQ);
  _Float16* DhT = (_Float16*)(ws + OFF_DHT);
  _Float16* QT  = (_Float16*)(ws + OFF_QT);
  float*    rm  = (float*)(ws + OFF_RM);
  float*    ri  = (float*)(ws + OFF_RI);
  float*    cm  = (float*)(ws + OFF_CM);
  float*    ci  = (float*)(ws + OFF_CI);
  int*      ql  = (int*)(ws + OFF_QLEN);
  float*    rpm = (float*)(ws + OFF_RPM);
  float*    rps = (float*)(ws + OFF_RPS);
  float*    cpm = (float*)(ws + OFF_CPM);
  float*    cps = (float*)(ws + OFF_CPS);

  k_qlens<<<1, 256, 0, stream>>>(qmask, ql);
  k_cast<<<6144, 256, 0, stream>>>(Dp, Qp, dlens, Dh, Dl, Qh, Ql, DhT, QT, out);
  k_gemm_scores<<<512, 256, 0, stream>>>(Dh, Dl, Qh, Ql, S, ql, dlens, rpm, rps, cpm, cps);
  k_merge<<<96, 256, 0, stream>>>(rpm, rps, cpm, cps, rm, ri, cm, ci);
  k_normalize<<<2048, 256, 0, stream>>>(S, rm, ri, cm, ci, ql, dlens, Ad, Aq);
  k_gemm_cq<<<512, 256, 0, stream>>>(Aq, DhT, QT, out);
  k_gemm_cd<<<2048, 256, 0, stream>>>(Ad, QT, dlens, out);
}